// Round 2
// baseline (6195.293 us; speedup 1.0000x reference)
//
#include <hip/hip_runtime.h>

typedef short bf8 __attribute__((ext_vector_type(8)));   // 8 bf16 raw bits (4 VGPRs)
typedef float f4  __attribute__((ext_vector_type(4)));
typedef int   i4  __attribute__((ext_vector_type(4)));

#define DEV static __device__ __forceinline__

DEV float bf2f(unsigned short u){ unsigned int x = ((unsigned int)u) << 16; float f; __builtin_memcpy(&f, &x, 4); return f; }
DEV unsigned short f2bf(float f){ unsigned int x; __builtin_memcpy(&x, &f, 4); unsigned int r = (x + 0x7fffu + ((x >> 16) & 1u)) >> 16; return (unsigned short)r; }
DEV float sigm(float z){ return 1.f / (1.f + __expf(-z)); }
DEV float tanh_fast(float z){ float e = __expf(2.f * z); return 1.f - 2.f / (e + 1.f); }

// ---------------------------------------------------------------- cvt f32->bf16
__global__ void k_cvt(const float* __restrict__ s, unsigned short* __restrict__ d, int n){
    int i = blockIdx.x * 256 + threadIdx.x;
    if (i < n) d[i] = f2bf(s[i]);
}

// transpose-cvt for Wp [256,256]: d[e*256+h] = s[h*256+e]
__global__ void k_cvt_t(const float* __restrict__ s, unsigned short* __restrict__ d){
    int e = blockIdx.x, h = threadIdx.x;
    d[e * 256 + h] = f2bf(s[h * 256 + e]);
}

// fused bias: bc[g<1024] = b0f[g] + Wi0f[g,:]@bp ; bc[g>=1024] = b0r[g-1024] + Wi0r[g-1024,:]@bp
__global__ void k_bias(const float* __restrict__ b0f, const float* __restrict__ Wi0f,
                       const float* __restrict__ b0r, const float* __restrict__ Wi0r,
                       const float* __restrict__ bp, float* __restrict__ bc){
    int g = blockIdx.x * 256 + threadIdx.x;
    const float* b = (g < 1024) ? b0f : b0r;
    const float* W = ((g < 1024) ? Wi0f : Wi0r) + (size_t)(g & 1023) * 256;
    float a = b[g & 1023];
    for (int k = 0; k < 256; ++k) a += W[k] * bp[k];
    bc[g] = a;
}

// ---------------------------------------------------------------- GEMM: C[M,N] = A[arow(m),:K] @ W[N,K]^T + bias[n]
// AMODE: 0 arow=m | 2 chunk-fwd + seq-gather | 3 chunk-rev + seq-gather | 4 chunk-fwd direct | 5 chunk-rev direct
// chunk modes: p=m>>5, ss=m&31, t = t0+ss (fwd) or t0-ss (rev), arow = p*256+t (then seq[] if gather).
// 128x128 tile, BK=32, 4 waves, each wave 64x64 (4x4 frags of 16x16x32 MFMA).
template<int K, int AMODE, bool OUTH>
__global__ __launch_bounds__(256)
void k_gemm(const unsigned short* __restrict__ A, const int* __restrict__ seq,
            const unsigned short* __restrict__ W, const float* __restrict__ bias,
            void* __restrict__ C, int N, int t0)
{
    __shared__ unsigned short Alds[128 * 32];
    __shared__ unsigned short Blds[128 * 32];
    const int tid = threadIdx.x, lane = tid & 63, wv = tid >> 6;
    const long m0 = (long)blockIdx.x * 128, n0 = (long)blockIdx.y * 128;

    // staging: 2 chunks (16B) per matrix per thread; LDS[r][kb] holds G[r][kb ^ ((r>>1)&3)]
    const unsigned short* srcA[2]; const unsigned short* srcB[2]; int ldsOfs[2];
    #pragma unroll
    for (int q = 0; q < 2; ++q){
        int c = wv * 128 + q * 64 + lane;
        int r = c >> 2, kb = c & 3;
        int kg = kb ^ ((r >> 1) & 3);
        long m = m0 + r;
        long arow;
        if constexpr (AMODE == 0){
            arow = m;
        } else {
            long p = m >> 5; int ss = (int)(m & 31);
            int t = (AMODE == 2 || AMODE == 4) ? (t0 + ss) : (t0 - ss);
            arow = p * 256 + t;
            if constexpr (AMODE == 2 || AMODE == 3) arow = seq[arow];
        }
        srcA[q] = A + arow * K + kg * 8;
        srcB[q] = W + (n0 + r) * K + kg * 8;
        ldsOfs[q] = c * 8;
    }
    f4 acc[4][4] = {};
    const int ar = lane & 15, kq = lane >> 4;
    const int wm = (wv >> 1) * 64, wn = (wv & 1) * 64;

    for (int kk = 0; kk < K / 32; ++kk){
        i4 ra[2], rb[2];
        #pragma unroll
        for (int q = 0; q < 2; ++q){
            ra[q] = *(const i4*)(srcA[q] + kk * 32);
            rb[q] = *(const i4*)(srcB[q] + kk * 32);
        }
        __syncthreads();   // previous iteration's compute done
        #pragma unroll
        for (int q = 0; q < 2; ++q){
            *(i4*)&Alds[ldsOfs[q]] = ra[q];
            *(i4*)&Blds[ldsOfs[q]] = rb[q];
        }
        __syncthreads();
        bf8 af[4], bfr[4];
        #pragma unroll
        for (int mt = 0; mt < 4; ++mt){
            int row = wm + mt * 16 + ar; int ph = kq ^ ((row >> 1) & 3);
            af[mt] = __builtin_bit_cast(bf8, *(const i4*)&Alds[row * 32 + ph * 8]);
        }
        #pragma unroll
        for (int nt = 0; nt < 4; ++nt){
            int row = wn + nt * 16 + ar; int ph = kq ^ ((row >> 1) & 3);
            bfr[nt] = __builtin_bit_cast(bf8, *(const i4*)&Blds[row * 32 + ph * 8]);
        }
        #pragma unroll
        for (int mt = 0; mt < 4; ++mt)
            #pragma unroll
            for (int nt = 0; nt < 4; ++nt)
                acc[mt][nt] = __builtin_amdgcn_mfma_f32_16x16x32_bf16(af[mt], bfr[nt], acc[mt][nt], 0, 0, 0);
    }
    // epilogue: C row = (lane>>4)*4 + reg, col = lane&15 (m89-verified layout)
    #pragma unroll
    for (int nt = 0; nt < 4; ++nt){
        long n = n0 + wn + nt * 16 + ar;
        float bv = bias[n];
        #pragma unroll
        for (int mt = 0; mt < 4; ++mt){
            #pragma unroll
            for (int r = 0; r < 4; ++r){
                long m = m0 + wm + mt * 16 + kq * 4 + r;
                float v = acc[mt][nt][r] + bv;
                if (OUTH) ((_Float16*)C)[m * N + n] = (_Float16)v;
                else      ((unsigned short*)C)[m * N + n] = f2bf(v);
            }
        }
    }
}

// ---------------------------------------------------------------- LSTM step
// grid (8 ptiles, 8 hcol-chunks, 2 dirs), block 256 (4 waves, 16 paths each).
// z = h_prev @ Wh_slice^T (MFMA) + zx-chunk; updates c/h for its own (path,hcol) cells.
template<int LAYER>
__global__ __launch_bounds__(256)
void k_step(int s, const unsigned short* __restrict__ Wh,   // [2][1024][256] bf16
            const _Float16* __restrict__ zxF,               // [512][32][1024] fwd chunk
            const _Float16* __restrict__ zxR,               // [512][32][1024] rev chunk
            unsigned short* __restrict__ o0,                // [512*256][512] bf16 (layer0 h history)
            const unsigned short* __restrict__ hsR, unsigned short* __restrict__ hsW, // layer1 ping-pong [2][512][256]
            float* __restrict__ cbuf,                       // [2][512][256]
            const int* __restrict__ lengths)
{
    __shared__ unsigned short Wlds[128 * 256];  // 64KB; LDS[r][kb] = G[r][kb ^ (r&7)] (16B units)
    const int tid = threadIdx.x, lane = tid & 63, wv = tid >> 6;
    const int pt = blockIdx.x, jc = blockIdx.y, dir = blockIdx.z;
    const int t = dir ? 255 - s : s;
    const int tprev = dir ? t + 1 : t - 1;

    if (s > 0){
        for (int c = tid; c < 4096; c += 256){
            int r = c >> 5, kb = c & 31;
            int kg = kb ^ (r & 7);
            int wrow = (r >> 5) * 256 + jc * 32 + (r & 31);
            *(i4*)&Wlds[c * 8] = *(const i4*)&Wh[((size_t)(dir * 1024 + wrow)) * 256 + kg * 8];
        }
    }
    __syncthreads();

    const int ar = lane & 15, kq = lane >> 4;
    const int p0 = pt * 64 + wv * 16 + ar;
    f4 acc[8] = {};
    if (s > 0){
        bf8 af[8];
        const unsigned short* hp;
        if constexpr (LAYER == 0) hp = o0 + ((size_t)(p0 * 256 + tprev)) * 512 + dir * 256;
        else                      hp = hsR + ((size_t)(dir * 512 + p0)) * 256;
        #pragma unroll
        for (int k0 = 0; k0 < 8; ++k0)
            af[k0] = __builtin_bit_cast(bf8, *(const i4*)&hp[k0 * 32 + kq * 8]);
        #pragma unroll
        for (int nt = 0; nt < 8; ++nt){
            int row = nt * 16 + ar;
            #pragma unroll
            for (int k0 = 0; k0 < 8; ++k0){
                int ph = (k0 * 4 + kq) ^ (row & 7);
                bf8 b = __builtin_bit_cast(bf8, *(const i4*)&Wlds[row * 256 + ph * 8]);
                acc[nt] = __builtin_amdgcn_mfma_f32_16x16x32_bf16(af[k0], b, acc[nt], 0, 0, 0);
            }
        }
    }
    // epilogue: nt = gate*2 + sub; C row = kq*4+r (path), col = ar
    const _Float16* zb = dir ? zxR : zxF;
    const int ss = s & 31;
    #pragma unroll
    for (int sub = 0; sub < 2; ++sub){
        const int hcol = jc * 32 + sub * 16 + ar;
        #pragma unroll
        for (int r = 0; r < 4; ++r){
            const int path = pt * 64 + wv * 16 + kq * 4 + r;
            const size_t zofs = (((size_t)path << 5) + ss) * 1024 + hcol;
            float zi = acc[0 + sub][r] + (float)zb[zofs];
            float zf = acc[2 + sub][r] + (float)zb[zofs + 256];
            float zg = acc[4 + sub][r] + (float)zb[zofs + 512];
            float zo = acc[6 + sub][r] + (float)zb[zofs + 768];
            const bool m = t < lengths[path];
            float* cp = cbuf + ((size_t)(dir * 512 + path)) * 256 + hcol;
            float cold = *cp;
            float ig = sigm(zi), fg = sigm(zf), gg = tanh_fast(zg), og = sigm(zo);
            float cn = fg * cold + ig * gg;
            float hn = og * tanh_fast(cn);
            float hold = 0.f;
            if (s > 0){
                if constexpr (LAYER == 0) hold = bf2f(o0[((size_t)path * 256 + tprev) * 512 + dir * 256 + hcol]);
                else                      hold = bf2f(hsR[((size_t)(dir * 512 + path)) * 256 + hcol]);
            }
            if (m) *cp = cn;
            float ho = m ? hn : hold;
            if constexpr (LAYER == 0) o0[((size_t)path * 256 + t) * 512 + dir * 256 + hcol] = f2bf(ho);
            else                      hsW[((size_t)(dir * 512 + path)) * 256 + hcol] = f2bf(ho);
        }
    }
}

// ---------------------------------------------------------------- head: path_feat + fuse + score
__global__ __launch_bounds__(256)
void k_fuse(const unsigned short* __restrict__ hsF,  // [2][512][256] final layer-1 hidden
            const float* __restrict__ features, const float* __restrict__ Wf, const float* __restrict__ bfv,
            const float* __restrict__ Wfus, const float* __restrict__ bfus,
            const float* __restrict__ Wa, const float* __restrict__ ba,
            float* __restrict__ pe, float* __restrict__ scores)
{
    __shared__ float comb[768];
    __shared__ float fl[64];
    __shared__ float red[256];
    const int p = blockIdx.x, tid = threadIdx.x;
    comb[tid]       = bf2f(hsF[(size_t)(0 * 512 + p) * 256 + tid]);
    comb[256 + tid] = bf2f(hsF[(size_t)(1 * 512 + p) * 256 + tid]);
    if (tid < 64) fl[tid] = features[p * 64 + tid];
    __syncthreads();
    float pf = bfv[tid];
    #pragma unroll 4
    for (int k = 0; k < 64; ++k) pf += fl[k] * Wf[tid * 64 + k];
    comb[512 + tid] = pf;
    __syncthreads();
    float a = bfus[tid];
    #pragma unroll 4
    for (int k = 0; k < 768; ++k) a += comb[k] * Wfus[tid * 768 + k];
    float pev = fmaxf(a, 0.f);
    pe[(size_t)p * 256 + tid] = pev;
    red[tid] = pev * Wa[tid];
    __syncthreads();
    for (int ofs = 128; ofs > 0; ofs >>= 1){
        if (tid < ofs) red[tid] += red[tid + ofs];
        __syncthreads();
    }
    if (tid == 0) scores[p] = red[0] + ba[0];
}

// ---------------------------------------------------------------- head: softmax + aggregate + MLP
__global__ __launch_bounds__(512)
void k_head(const float* __restrict__ pe, const float* __restrict__ scores,
            const float* __restrict__ W1, const float* __restrict__ b1,
            const float* __restrict__ W2, const float* __restrict__ b2,
            float* __restrict__ out)
{
    __shared__ float att[512];
    __shared__ float red[512];
    __shared__ float agg[768];
    __shared__ float h1[512];
    const int tid = threadIdx.x;
    float s = scores[tid];
    red[tid] = s; __syncthreads();
    for (int ofs = 256; ofs > 0; ofs >>= 1){ if (tid < ofs) red[tid] = fmaxf(red[tid], red[tid + ofs]); __syncthreads(); }
    float mx = red[0]; __syncthreads();
    float e = __expf(s - mx);
    red[tid] = e; __syncthreads();
    for (int ofs = 256; ofs > 0; ofs >>= 1){ if (tid < ofs) red[tid] += red[tid + ofs]; __syncthreads(); }
    float sum = red[0]; __syncthreads();
    att[tid] = e / sum;
    __syncthreads();
    if (tid < 256){
        float w = 0.f, sm = 0.f, mxv = -1e30f;
        for (int p = 0; p < 512; ++p){
            float v = pe[(size_t)p * 256 + tid];
            w += att[p] * v; sm += v; mxv = fmaxf(mxv, v);
        }
        agg[tid] = w; agg[256 + tid] = sm * (1.f / 512.f); agg[512 + tid] = mxv;
    }
    __syncthreads();
    float hv = b1[tid];
    #pragma unroll 4
    for (int k = 0; k < 768; ++k) hv += agg[k] * W1[tid * 768 + k];
    hv = fmaxf(hv, 0.f);
    h1[tid] = hv;
    __syncthreads();
    if (tid < 256){
        float o = b2[tid];
        #pragma unroll 4
        for (int k = 0; k < 512; ++k) o += h1[k] * W2[tid * 512 + k];
        out[tid] = o;
    }
}

// ----------------------------------------------------------------
extern "C" void kernel_launch(void* const* d_in, const int* in_sizes, int n_in,
                              void* d_out, int out_size, void* d_ws, size_t ws_size,
                              hipStream_t stream)
{
    const int*   seq  = (const int*)  d_in[0];
    const int*   len  = (const int*)  d_in[1];
    const float* feat = (const float*)d_in[2];
    const float* emb  = (const float*)d_in[3];
    const float* Wp   = (const float*)d_in[5];
    const float* bp   = (const float*)d_in[6];
    const float* Wi0f = (const float*)d_in[7];
    const float* Wh0f = (const float*)d_in[8];
    const float* b0f  = (const float*)d_in[9];
    const float* Wi0r = (const float*)d_in[10];
    const float* Wh0r = (const float*)d_in[11];
    const float* b0r  = (const float*)d_in[12];
    const float* Wi1f = (const float*)d_in[13];
    const float* Wh1f = (const float*)d_in[14];
    const float* b1f  = (const float*)d_in[15];
    const float* Wi1r = (const float*)d_in[16];
    const float* Wh1r = (const float*)d_in[17];
    const float* b1r  = (const float*)d_in[18];
    const float* Wf   = (const float*)d_in[19];
    const float* bfv  = (const float*)d_in[20];
    const float* Wfus = (const float*)d_in[21];
    const float* bfus = (const float*)d_in[22];
    const float* Wa   = (const float*)d_in[23];
    const float* ba   = (const float*)d_in[24];
    const float* W1   = (const float*)d_in[25];
    const float* b1   = (const float*)d_in[26];
    const float* W2   = (const float*)d_in[27];
    const float* b2   = (const float*)d_in[28];

    char* ws = (char*)d_ws;
    size_t o = 0;
    auto alloc = [&](size_t bytes)->char*{ char* r = ws + o; o += (bytes + 255) & ~(size_t)255; return r; };

    unsigned short* emb_bf = (unsigned short*)alloc(50000UL * 256 * 2);   // 25.6 MB
    unsigned short* wpT    = (unsigned short*)alloc(256UL * 256 * 2);
    unsigned short* wi0b   = (unsigned short*)alloc(2048UL * 256 * 2);
    unsigned short* wc0    = (unsigned short*)alloc(2048UL * 256 * 2);    // (Wi0·Wp) bf16
    float*          bc0    = (float*)        alloc(2048UL * 4);           // b0 + Wi0·bp
    float*          zbias  = (float*)        alloc(256UL * 4);
    unsigned short* wi1b   = (unsigned short*)alloc(2048UL * 512 * 2);
    unsigned short* wh0b   = (unsigned short*)alloc(2048UL * 256 * 2);
    unsigned short* wh1b   = (unsigned short*)alloc(2048UL * 256 * 2);
    unsigned short* o0p    = (unsigned short*)alloc(131072UL * 512 * 2);  // 128 MB
    _Float16*       zxF    = (_Float16*)     alloc(512UL * 32 * 1024 * 2); // 32 MB
    _Float16*       zxR    = (_Float16*)     alloc(512UL * 32 * 1024 * 2); // 32 MB
    float*          c0p    = (float*)        alloc(2UL * 512 * 256 * 4);
    float*          c1p    = (float*)        alloc(2UL * 512 * 256 * 4);
    unsigned short* hsA    = (unsigned short*)alloc(2UL * 512 * 256 * 2);
    unsigned short* hsB    = (unsigned short*)alloc(2UL * 512 * 256 * 2);
    float*          pe     = (float*)        alloc(512UL * 256 * 4);
    float*          scores = (float*)        alloc(512UL * 4);
    (void)in_sizes; (void)n_in; (void)out_size;
    if (o > ws_size) return;   // workspace too small: fail cleanly, do not touch memory

    auto cvt = [&](const float* s, unsigned short* d, int n){
        k_cvt<<<(n + 255) / 256, 256, 0, stream>>>(s, d, n);
    };
    cvt(emb,  emb_bf, 50000 * 256);
    k_cvt_t<<<256, 256, 0, stream>>>(Wp, wpT);
    cvt(Wi0f, wi0b,              1024 * 256);
    cvt(Wi0r, wi0b + 1024 * 256, 1024 * 256);
    cvt(Wh0f, wh0b,              1024 * 256);
    cvt(Wh0r, wh0b + 1024 * 256, 1024 * 256);
    cvt(Wi1f, wi1b,              1024 * 512);
    cvt(Wi1r, wi1b + 1024 * 512, 1024 * 512);
    cvt(Wh1f, wh1b,              1024 * 256);
    cvt(Wh1r, wh1b + 1024 * 256, 1024 * 256);
    k_bias<<<8, 256, 0, stream>>>(b0f, Wi0f, b0r, Wi0r, bp, bc0);
    hipMemsetAsync(zbias, 0, 256 * 4, stream);
    hipMemsetAsync(c0p, 0, 2UL * 512 * 256 * 4, stream);
    hipMemsetAsync(c1p, 0, 2UL * 512 * 256 * 4, stream);

    // Wc0[2048,256] = wi0b @ wpT^T   (fused projection weight)
    k_gemm<256, 0, false><<<dim3(16, 2), 256, 0, stream>>>(wi0b, nullptr, wpT, zbias, wc0, 256, 0);

    // layer 0: per 32-step chunk, compute zx fwd/rev slices then run the steps
    for (int c = 0; c < 8; ++c){
        int s0 = c * 32;
        k_gemm<256, 2, true><<<dim3(128, 8), 256, 0, stream>>>(emb_bf, seq, wc0,              bc0,        zxF, 1024, s0);
        k_gemm<256, 3, true><<<dim3(128, 8), 256, 0, stream>>>(emb_bf, seq, wc0 + 1024 * 256, bc0 + 1024, zxR, 1024, 255 - s0);
        for (int s = s0; s < s0 + 32; ++s)
            k_step<0><<<dim3(8, 8, 2), 256, 0, stream>>>(s, wh0b, zxF, zxR, o0p, nullptr, nullptr, c0p, len);
    }
    // layer 1
    for (int c = 0; c < 8; ++c){
        int s0 = c * 32;
        k_gemm<512, 4, true><<<dim3(128, 8), 256, 0, stream>>>(o0p, nullptr, wi1b,              b1f, zxF, 1024, s0);
        k_gemm<512, 5, true><<<dim3(128, 8), 256, 0, stream>>>(o0p, nullptr, wi1b + 1024 * 512, b1r, zxR, 1024, 255 - s0);
        for (int s = s0; s < s0 + 32; ++s)
            k_step<1><<<dim3(8, 8, 2), 256, 0, stream>>>(s, wh1b, zxF, zxR, nullptr,
                (s & 1) ? hsA : hsB, (s & 1) ? hsB : hsA, c1p, len);
    }
    // head
    k_fuse<<<512, 256, 0, stream>>>(hsB, feat, Wf, bfv, Wfus, bfus, Wa, ba, pe, scores);
    k_head<<<1, 512, 0, stream>>>(pe, scores, W1, b1, W2, b2, (float*)d_out);
}